// Round 14
// baseline (122.267 us; speedup 1.0000x reference)
//
#include <hip/hip_runtime.h>
#include <math.h>

typedef __attribute__((ext_vector_type(8))) short short8;
typedef __attribute__((ext_vector_type(4))) float f32x4;
typedef __attribute__((ext_vector_type(4))) unsigned short us4;

constexpr int NB = 16, NS = 512, NT = 4096, IND0 = 512;
constexpr int NROW = NB * NS;        // 8192 phoneme rows
constexpr int GSLAB = NROW * 256;    // elements per G slab
constexpr int NGEMM = (NROW / 64) * 6;   // 768 gemm blocks
constexpr int NUP = NB * NT / 64;        // 1024 up-writer blocks

__device__ __forceinline__ unsigned short f2bf(float f) {
    __bf16 h = (__bf16)f;
    return __builtin_bit_cast(unsigned short, h);
}
__device__ __forceinline__ float bf2f(unsigned short h) {
    return __uint_as_float(((unsigned)h) << 16);
}

// ---------------------------------------------------------------------------
// Merged prep kernel (vectorized writers):
//  [0,16)      : per-batch cumsum + frame->phoneme idx table
//  [16,1040)   : emb f32 -> bf16 cast (2 short8 per thread)
//  [1040,1424) : Wall fragments (6 slabs: dp taps 0-2, f0 taps 0-2)
//  [1424,1520) : Bs2 fragments (dp_w2, K=768)
__global__ __launch_bounds__(256)
void prep_kernel(const float* __restrict__ emb, const int* __restrict__ dur,
                 const float* __restrict__ dp_w1, const float* __restrict__ dp_w2,
                 const float* __restrict__ f0_w1,
                 unsigned short* __restrict__ emb_bf, int* __restrict__ idxarr,
                 unsigned short* __restrict__ Ball, unsigned short* __restrict__ Bs2) {
    const int bid = blockIdx.x, t = threadIdx.x;
    if (bid < 16) {
        __shared__ int cs[NS];
        __shared__ int wsum[4];
        int b = bid, w = t >> 6, lane = t & 63;
        int v0 = dur[b * NS + t * 2], v1 = dur[b * NS + t * 2 + 1];
        int incl = v0 + v1;
        for (int off = 1; off < 64; off <<= 1) {
            int n = __shfl_up(incl, off, 64);
            if (lane >= off) incl += n;
        }
        if (lane == 63) wsum[w] = incl;
        __syncthreads();
        int pre = 0;
        #pragma unroll
        for (int i = 0; i < 4; ++i) if (i < w) pre += wsum[i];
        incl += pre;
        cs[t * 2] = incl - v1;
        cs[t * 2 + 1] = incl;
        __syncthreads();
        int total = cs[NS - 1];
        for (int f = t; f < NT; f += 256) {
            int lo = 0, hi = NS;
            while (lo < hi) {
                int mid = (lo + hi) >> 1;
                if (cs[mid] <= f) lo = mid + 1; else hi = mid;
            }
            idxarr[b * NT + f] = (f < total) ? (lo < NS ? lo : NS - 1) : -1;
        }
    } else if (bid < 1040) {
        int i0 = (bid - 16) * 256 + t;     // short8 index; 2 per thread
        #pragma unroll
        for (int rep = 0; rep < 2; ++rep) {
            int i = i0 + rep * 262144;
            const float4* p = (const float4*)(emb + (size_t)i * 8);
            float4 a0 = p[0], a1 = p[1];
            short8 o;
            o[0] = (short)f2bf(a0.x); o[1] = (short)f2bf(a0.y);
            o[2] = (short)f2bf(a0.z); o[3] = (short)f2bf(a0.w);
            o[4] = (short)f2bf(a1.x); o[5] = (short)f2bf(a1.y);
            o[6] = (short)f2bf(a1.z); o[7] = (short)f2bf(a1.w);
            *(short8*)(emb_bf + (size_t)i * 8) = o;
        }
    } else if (bid < 1424) {
        int gidx8 = (bid - 1040) * 256 + t;
        int q = gidx8 >> 14;
        int r8 = gidx8 & 16383;
        int l  = r8 & 63;
        int s2 = (r8 >> 6) & 1;
        int nf = (r8 >> 7) & 3;
        int w  = (r8 >> 9) & 3;
        int st = r8 >> 11;                  // [0,8)
        int k0  = st * 64 + s2 * 32 + ((l >> 4) << 3);
        int col = w * 64 + nf * 16 + (l & 15);
        int tap = q < 3 ? q : q - 3;
        const float* srcw = q < 3 ? dp_w1 : f0_w1;
        const float* sp = srcw + (size_t)(col * 512 + k0) * 3 + tap;
        short8 o;
        #pragma unroll
        for (int e = 0; e < 8; ++e) o[e] = (short)f2bf(sp[e * 3]);
        *(short8*)(Ball + (size_t)q * 131072 + (size_t)r8 * 8) = o;
    } else {
        int r8 = (bid - 1424) * 256 + t;
        int l  = r8 & 63;
        int s2 = (r8 >> 6) & 1;
        int nf = (r8 >> 7) & 3;
        int w  = (r8 >> 9) & 3;
        int st = r8 >> 11;                  // [0,12)
        int k0  = st * 64 + s2 * 32 + ((l >> 4) << 3);
        int col = w * 64 + nf * 16 + (l & 15);
        int i0  = k0 & 255;
        int ko  = k0 >> 8;
        const float* sp = dp_w2 + (size_t)(col * 256 + i0) * 3 + ko;
        short8 o;
        #pragma unroll
        for (int e = 0; e < 8; ++e) o[e] = (short)f2bf(sp[e * 3]);
        *(short8*)(Bs2 + (size_t)r8 * 8) = o;
    }
}

// ---------------------------------------------------------------------------
// Merged compute+stream kernel:
//  [0,768)     : GEMM  G[q] = emb_bf (8192x512) x Wall[q] (512x256)
//  [768,1792)  : up-writer (exact f32 copy of emb rows per frame)
// MFMA-bound gemm waves and store-bound up waves co-resident per CU (m114).
__global__ __launch_bounds__(256, 3)
void guw_kernel(const float* __restrict__ emb,
                const unsigned short* __restrict__ emb_bf,
                const int* __restrict__ idxarr,
                const unsigned short* __restrict__ Ball,
                unsigned short* __restrict__ G, float* __restrict__ up) {
    constexpr int NSTEP = 8;
    constexpr int BUFS = 64 * 64;
    __shared__ unsigned short smem[64 * 256];   // gemm: 2 A-bufs | H tile; up: il

    const int t = threadIdx.x;
    const int bid = blockIdx.x;

    if (bid < NGEMM) {
        const int q = bid % 6;
        const int m0 = (bid / 6) * 64;
        const int w = t >> 6, l = t & 63, llo = l & 15, lhi = l >> 4;
        const int arow = t >> 2, sub = t & 3;
        const unsigned short* Bq = Ball + (size_t)q * 131072;
        unsigned short* Gq = G + (size_t)q * GSLAB;

        f32x4 acc[4][4];
        #pragma unroll
        for (int i = 0; i < 4; ++i)
            #pragma unroll
            for (int j = 0; j < 4; ++j) acc[i][j] = (f32x4){0.f, 0.f, 0.f, 0.f};

        short8 a[2];
        short8 b0[8], b1[8];

        auto stageA = [&](int st) {
            const unsigned short* p =
                emb_bf + (size_t)(m0 + arow) * 512 + st * 64 + sub * 16;
            a[0] = *(const short8*)p;
            a[1] = *(const short8*)(p + 8);
        };
        auto dsWriteA = [&](int st) {
            int buf = (st & 1) * BUFS;
            *(short8*)&smem[buf + arow * 64 + (((sub * 2 + 0) ^ (arow & 7)) << 3)] = a[0];
            *(short8*)&smem[buf + arow * 64 + (((sub * 2 + 1) ^ (arow & 7)) << 3)] = a[1];
        };
        auto loadB = [&](int st, short8* bb) {
            const unsigned short* base = Bq + ((size_t)(st * 4 + w) * 8) * 512 + l * 8;
            #pragma unroll
            for (int s = 0; s < 2; ++s)
                #pragma unroll
                for (int nf = 0; nf < 4; ++nf)
                    bb[s * 4 + nf] = *(const short8*)(base + (nf * 2 + s) * 512);
        };
        auto mfmaPhase = [&](int buf, short8* bc) {
            #pragma unroll
            for (int s = 0; s < 2; ++s)
                #pragma unroll
                for (int mf = 0; mf < 4; ++mf) {
                    int row = mf * 16 + llo;
                    short8 af = *(const short8*)&smem[buf + row * 64 +
                                                     ((((s << 2) | lhi) ^ (row & 7)) << 3)];
                    #pragma unroll
                    for (int nf = 0; nf < 4; ++nf)
                        acc[mf][nf] = __builtin_amdgcn_mfma_f32_16x16x32_bf16(
                            af, bc[s * 4 + nf], acc[mf][nf], 0, 0, 0);
                }
        };

        stageA(0);
        dsWriteA(0);
        stageA(1);
        loadB(0, b0);
        __syncthreads();
        for (int st = 0; st < NSTEP; st += 2) {
            loadB(st + 1, b1);
            dsWriteA(st + 1);
            if (st + 2 < NSTEP) stageA(st + 2);
            mfmaPhase(0, b0);
            __syncthreads();
            if (st + 2 < NSTEP) {
                loadB(st + 2, b0);
                dsWriteA(st + 2);
            }
            if (st + 3 < NSTEP) stageA(st + 3);
            mfmaPhase(BUFS, b1);
            __syncthreads();
        }

        unsigned short* H = smem;
        #pragma unroll
        for (int nf = 0; nf < 4; ++nf) {
            int col = w * 64 + nf * 16 + llo;
            #pragma unroll
            for (int mf = 0; mf < 4; ++mf)
                #pragma unroll
                for (int r = 0; r < 4; ++r) {
                    int row = mf * 16 + lhi * 4 + r;
                    H[row * 256 + ((((col >> 2) ^ (row & 15)) << 2) | (col & 3))] =
                        f2bf(acc[mf][nf][r]);
                }
        }
        __syncthreads();
        #pragma unroll
        for (int it = 0; it < 16; ++it) {
            int lin = it * 256 + t;
            int row = lin >> 6, g = lin & 63;
            us4 hv = *(const us4*)&H[row * 256 + ((g ^ (row & 15)) << 2)];
            *(us4*)&Gq[(size_t)(m0 + row) * 256 + g * 4] = hv;
        }
    } else {
        // --- up-writer: 64 frames per block, exact f32 copy (0 if masked) ---
        int* il = (int*)smem;
        const int row0 = (bid - NGEMM) * 64;
        const int b = row0 >> 12;
        if (t < 64) il[t] = idxarr[row0 + t];
        __syncthreads();
        for (int c = t; c < 64 * 128; c += 256) {
            int r = c >> 7, j = c & 127;
            int ix = il[r];
            float4 v = make_float4(0.f, 0.f, 0.f, 0.f);
            if (ix >= 0)
                v = ((const float4*)(emb + ((size_t)(b * NS + ix)) * IND0))[j];
            ((float4*)(up + (size_t)(row0 + r) * IND0))[j] = v;
        }
    }
}

// ---------------------------------------------------------------------------
// f0 combine: sum 3 G rows (slabs 3-5) + bias + relu + LN + head dot -> pf0.
__global__ __launch_bounds__(256, 4)
void f0c_kernel(const int* __restrict__ idxarr,
                const unsigned short* __restrict__ G,
                const float* __restrict__ f0_b1, const float* __restrict__ f0_g1,
                const float* __restrict__ f0_be1, const float* __restrict__ f0_w2,
                const float* __restrict__ f0_b2, float* __restrict__ pf0) {
    __shared__ int il[66];
    const int t = threadIdx.x;
    const int row0 = blockIdx.x * 64;
    const int b = row0 >> 12, t0 = row0 & (NT - 1);

    for (int j = t; j < 66; j += 256) {
        int tf = t0 + j - 1;
        il[j] = (tf >= 0 && tf < NT) ? idxarr[b * NT + tf] : -1;
    }
    __syncthreads();

    const unsigned short* Gf = G + (size_t)3 * GSLAB;
    int r = t >> 2, jj = t & 3;
    int grow = row0 + r;
    f32x4 v[16];
    #pragma unroll
    for (int c = 0; c < 16; ++c) v[c] = (f32x4){0.f, 0.f, 0.f, 0.f};
    #pragma unroll
    for (int k = 0; k < 3; ++k) {
        int ix = il[r + k];
        if (ix >= 0) {
            const unsigned short* Gr = Gf + (size_t)k * GSLAB
                                     + (size_t)(b * NS + ix) * 256 + jj * 64;
            #pragma unroll
            for (int c = 0; c < 16; ++c) {
                us4 hv = *(const us4*)(Gr + c * 4);
                v[c][0] += bf2f(hv[0]); v[c][1] += bf2f(hv[1]);
                v[c][2] += bf2f(hv[2]); v[c][3] += bf2f(hv[3]);
            }
        }
    }
    float sum = 0.f, sq = 0.f;
    #pragma unroll
    for (int c = 0; c < 16; ++c) {
        float4 bv = *(const float4*)&f0_b1[jj * 64 + c * 4];
        #pragma unroll
        for (int e = 0; e < 4; ++e) {
            float x = v[c][e] + ((const float*)&bv)[e];
            x = x > 0.f ? x : 0.f;
            v[c][e] = x;
            sum += x; sq += x * x;
        }
    }
    sum += __shfl_xor(sum, 1); sq += __shfl_xor(sq, 1);
    sum += __shfl_xor(sum, 2); sq += __shfl_xor(sq, 2);
    float mean = sum * (1.f / 256.f);
    float rs = rsqrtf(sq * (1.f / 256.f) - mean * mean + 1e-5f);
    float part = 0.f;
    #pragma unroll
    for (int c = 0; c < 16; ++c) {
        float4 gv = *(const float4*)&f0_g1[jj * 64 + c * 4];
        float4 be = *(const float4*)&f0_be1[jj * 64 + c * 4];
        float4 wf = *(const float4*)&f0_w2[jj * 64 + c * 4];
        part += ((v[c][0] - mean) * rs * gv.x + be.x) * wf.x;
        part += ((v[c][1] - mean) * rs * gv.y + be.y) * wf.y;
        part += ((v[c][2] - mean) * rs * gv.z + be.z) * wf.z;
        part += ((v[c][3] - mean) * rs * gv.w + be.w) * wf.w;
    }
    part += __shfl_xor(part, 1);
    part += __shfl_xor(part, 2);
    if (jj == 0) pf0[grow] = part + f0_b2[0];
}

// ---------------------------------------------------------------------------
// Fused dp chain: build 34 h1 rows in LDS from G slabs 0-2 (combine+LN),
// one barrier, then barrier-free K loop (A-resident, B reg ping-pong) +
// LN + dur head. 32 output rows per block.
__global__ __launch_bounds__(256, 4)
void dpf_kernel(const unsigned short* __restrict__ G,
                const float* __restrict__ dp_b1, const float* __restrict__ dp_g1,
                const float* __restrict__ dp_be1,
                const unsigned short* __restrict__ Bs2,
                const float* __restrict__ bias2, const float* __restrict__ gamma2,
                const float* __restrict__ beta2,
                const float* __restrict__ wfin, const float* __restrict__ bfin,
                float* __restrict__ pdur) {
    constexpr int NSTEP = 12;
    __shared__ unsigned short A[34 * 256];
    __shared__ unsigned short H[32 * 256];

    const int t = threadIdx.x;
    const int m0 = blockIdx.x * 32;
    const int w = t >> 6, l = t & 63, llo = l & 15, lhi = l >> 4;

    {
        int sub = t & 7;
        for (int j = t >> 3; j < 34; j += 32) {
            int sm = (m0 & (NS - 1)) - 1 + j;
            bool rowv = (sm >= 0 && sm < NS);
            int m = m0 - 1 + j;
            f32x4 v[8];
            #pragma unroll
            for (int c = 0; c < 8; ++c) v[c] = (f32x4){0.f, 0.f, 0.f, 0.f};
            if (rowv) {
                #pragma unroll
                for (int k = 0; k < 3; ++k) {
                    int sp = sm + k - 1;
                    if (sp >= 0 && sp < NS) {
                        const unsigned short* Gr = G + (size_t)k * GSLAB
                                                 + (size_t)(m + k - 1) * 256 + sub * 32;
                        #pragma unroll
                        for (int c = 0; c < 8; ++c) {
                            us4 hv = *(const us4*)(Gr + c * 4);
                            v[c][0] += bf2f(hv[0]); v[c][1] += bf2f(hv[1]);
                            v[c][2] += bf2f(hv[2]); v[c][3] += bf2f(hv[3]);
                        }
                    }
                }
            }
            float sum = 0.f, sq = 0.f;
            #pragma unroll
            for (int c = 0; c < 8; ++c) {
                float4 bv = *(const float4*)&dp_b1[sub * 32 + c * 4];
                #pragma unroll
                for (int e = 0; e < 4; ++e) {
                    float x = v[c][e] + ((const float*)&bv)[e];
                    x = x > 0.f ? x : 0.f;
                    v[c][e] = x; sum += x; sq += x * x;
                }
            }
            #pragma unroll
            for (int off = 4; off >= 1; off >>= 1) {
                sum += __shfl_xor(sum, off);
                sq  += __shfl_xor(sq, off);
            }
            float mean = sum * (1.f / 256.f);
            float rs = rsqrtf(sq * (1.f / 256.f) - mean * mean + 1e-5f);
            #pragma unroll
            for (int cc = 0; cc < 4; ++cc) {
                int ch = sub * 4 + cc;
                float4 g0 = *(const float4*)&dp_g1[ch * 8];
                float4 g1 = *(const float4*)&dp_g1[ch * 8 + 4];
                float4 e0 = *(const float4*)&dp_be1[ch * 8];
                float4 e1 = *(const float4*)&dp_be1[ch * 8 + 4];
                short8 o;
                if (rowv) {
                    f32x4 lo = v[cc * 2], hi = v[cc * 2 + 1];
                    o[0] = (short)f2bf((lo[0] - mean) * rs * g0.x + e0.x);
                    o[1] = (short)f2bf((lo[1] - mean) * rs * g0.y + e0.y);
                    o[2] = (short)f2bf((lo[2] - mean) * rs * g0.z + e0.z);
                    o[3] = (short)f2bf((lo[3] - mean) * rs * g0.w + e0.w);
                    o[4] = (short)f2bf((hi[0] - mean) * rs * g1.x + e1.x);
                    o[5] = (short)f2bf((hi[1] - mean) * rs * g1.y + e1.y);
                    o[6] = (short)f2bf((hi[2] - mean) * rs * g1.z + e1.z);
                    o[7] = (short)f2bf((hi[3] - mean) * rs * g1.w + e1.w);
                } else {
                    o = short8{0,0,0,0,0,0,0,0};
                }
                *(short8*)&A[j * 256 + ((ch ^ (j & 7)) << 3)] = o;
            }
        }
    }
    __syncthreads();

    f32x4 acc[2][4];
    #pragma unroll
    for (int i = 0; i < 2; ++i)
        #pragma unroll
        for (int j = 0; j < 4; ++j) acc[i][j] = (f32x4){0.f, 0.f, 0.f, 0.f};

    short8 b0[8], b1[8];
    auto loadB = [&](int st, short8* bb) {
        const unsigned short* base = Bs2 + ((size_t)(st * 4 + w) * 8) * 512 + l * 8;
        #pragma unroll
        for (int s = 0; s < 2; ++s)
            #pragma unroll
            for (int nf = 0; nf < 4; ++nf)
                bb[s * 4 + nf] = *(const short8*)(base + (nf * 2 + s) * 512);
    };
    auto mfmaPhase = [&](int st, short8* bc) {
        int ko = st >> 2;
        int cb = (st & 3) << 3;
        #pragma unroll
        for (int s = 0; s < 2; ++s)
            #pragma unroll
            for (int mf = 0; mf < 2; ++mf) {
                int jr = mf * 16 + llo + ko;
                int ch = cb + ((s << 2) | lhi);
                short8 af = *(const short8*)&A[jr * 256 + ((ch ^ (jr & 7)) << 3)];
                #pragma unroll
                for (int nf = 0; nf < 4; ++nf)
                    acc[mf][nf] = __builtin_amdgcn_mfma_f32_16x16x32_bf16(
                        af, bc[s * 4 + nf], acc[mf][nf], 0, 0, 0);
            }
    };

    loadB(0, b0);
    for (int st = 0; st < NSTEP; st += 2) {
        loadB(st + 1, b1);
        mfmaPhase(st, b0);
        if (st + 2 < NSTEP) loadB(st + 2, b0);
        mfmaPhase(st + 1, b1);
    }

    #pragma unroll
    for (int nf = 0; nf < 4; ++nf) {
        int col = w * 64 + nf * 16 + llo;
        float bv = bias2[col];
        #pragma unroll
        for (int mf = 0; mf < 2; ++mf)
            #pragma unroll
            for (int r = 0; r < 4; ++r) {
                int row = mf * 16 + lhi * 4 + r;
                float x = acc[mf][nf][r] + bv;
                x = x > 0.f ? x : 0.f;
                H[row * 256 + ((((col >> 2) ^ (row & 15)) << 2) | (col & 3))] = f2bf(x);
            }
    }
    __syncthreads();

    int row = t >> 3, jj = t & 7;
    const unsigned short* Hr = H + row * 256;
    int rx = row & 15;
    float sum = 0.f, sq = 0.f;
    #pragma unroll
    for (int c4 = 0; c4 < 8; ++c4) {
        int g = jj * 8 + c4;
        us4 hv = *(const us4*)&Hr[(g ^ rx) << 2];
        #pragma unroll
        for (int e = 0; e < 4; ++e) { float f = bf2f(hv[e]); sum += f; sq += f * f; }
    }
    #pragma unroll
    for (int off = 4; off >= 1; off >>= 1) {
        sum += __shfl_xor(sum, off);
        sq  += __shfl_xor(sq, off);
    }
    float mean = sum * (1.f / 256.f);
    float rs = rsqrtf(sq * (1.f / 256.f) - mean * mean + 1e-5f);
    float part = 0.f;
    #pragma unroll
    for (int c4 = 0; c4 < 8; ++c4) {
        int g = jj * 8 + c4;
        us4 hv = *(const us4*)&Hr[(g ^ rx) << 2];
        float4 gv = *(const float4*)&gamma2[g * 4];
        float4 bv = *(const float4*)&beta2[g * 4];
        float4 wv = *(const float4*)&wfin[g * 4];
        part += ((bf2f(hv[0]) - mean) * rs * gv.x + bv.x) * wv.x;
        part += ((bf2f(hv[1]) - mean) * rs * gv.y + bv.y) * wv.y;
        part += ((bf2f(hv[2]) - mean) * rs * gv.z + bv.z) * wv.z;
        part += ((bf2f(hv[3]) - mean) * rs * gv.w + bv.w) * wv.w;
    }
    #pragma unroll
    for (int off = 4; off >= 1; off >>= 1) part += __shfl_xor(part, off);
    if (jj == 0) {
        float r = part + bfin[0];
        r = expf(r); r = r > 1.f ? r : 1.f;
        pdur[m0 + row] = r;
    }
}

// ---------------------------------------------------------------------------
extern "C" void kernel_launch(void* const* d_in, const int* in_sizes, int n_in,
                              void* d_out, int out_size, void* d_ws, size_t ws_size,
                              hipStream_t stream) {
    const float* emb    = (const float*)d_in[0];
    const int*   dur    = (const int*)  d_in[1];
    const float* dp_w1  = (const float*)d_in[2];
    const float* dp_b1  = (const float*)d_in[3];
    const float* dp_g1  = (const float*)d_in[4];
    const float* dp_be1 = (const float*)d_in[5];
    const float* dp_w2  = (const float*)d_in[6];
    const float* dp_b2  = (const float*)d_in[7];
    const float* dp_g2  = (const float*)d_in[8];
    const float* dp_be2 = (const float*)d_in[9];
    const float* dp_w3  = (const float*)d_in[10];
    const float* dp_b3  = (const float*)d_in[11];
    const float* f0_w1  = (const float*)d_in[12];
    const float* f0_b1  = (const float*)d_in[13];
    const float* f0_g1  = (const float*)d_in[14];
    const float* f0_be1 = (const float*)d_in[15];
    const float* f0_w2  = (const float*)d_in[16];
    const float* f0_b2  = (const float*)d_in[17];

    float* up   = (float*)d_out;                       // (16, 4096, 512)
    float* pdur = up + (size_t)NB * NT * IND0;         // (16, 512)
    float* pf0  = pdur + NB * NS;                      // (16, 4096)

    char* ws = (char*)d_ws;
    int*            idxarr = (int*)(ws);                          // 256 KB
    unsigned short* Ball   = (unsigned short*)(ws + 262144);      // 1.5 MB
    unsigned short* Bs2    = (unsigned short*)(ws + 1835008);     // 384 KB
    unsigned short* emb_bf = (unsigned short*)(ws + 6422528);     // 8 MB
    unsigned short* G      = (unsigned short*)(ws + 14811136);    // 24 MB

    prep_kernel<<<1520, 256, 0, stream>>>(emb, dur, dp_w1, dp_w2, f0_w1,
                                          emb_bf, idxarr, Ball, Bs2);

    // GEMM (G slabs) co-scheduled with the up-writer (independent outputs)
    guw_kernel<<<NGEMM + NUP, 256, 0, stream>>>(
        emb, emb_bf, idxarr, Ball, G, up);

    // f0 combine (reads G slabs 3-5)
    f0c_kernel<<<NB * NT / 64, 256, 0, stream>>>(
        idxarr, G, f0_b1, f0_g1, f0_be1, f0_w2, f0_b2, pf0);

    // fused dp chain (reads G slabs 0-2) -> pdur
    dpf_kernel<<<NROW / 32, 256, 0, stream>>>(
        G, dp_b1, dp_g1, dp_be1, Bs2, dp_b2, dp_g2, dp_be2,
        dp_w3, dp_b3, pdur);
}

// Round 15
// 118.638 us; speedup vs baseline: 1.0306x; 1.0306x over previous
//
#include <hip/hip_runtime.h>
#include <math.h>

typedef __attribute__((ext_vector_type(8))) short short8;
typedef __attribute__((ext_vector_type(4))) float f32x4;
typedef __attribute__((ext_vector_type(4))) unsigned short us4;

constexpr int NB = 16, NS = 512, NT = 4096, IND0 = 512;
constexpr int NROW = NB * NS;        // 8192 phoneme rows
constexpr int GSLAB = NROW * 256;    // elements per G slab
constexpr int NGEMM = (NROW / 64) * 6;   // 768 gemm blocks
constexpr int NUP = NB * NT / 64;        // 1024 up-writer blocks

__device__ __forceinline__ unsigned short f2bf(float f) {
    __bf16 h = (__bf16)f;
    return __builtin_bit_cast(unsigned short, h);
}
__device__ __forceinline__ float bf2f(unsigned short h) {
    return __uint_as_float(((unsigned)h) << 16);
}

// ---------------------------------------------------------------------------
// Merged prep kernel (vectorized writers):
//  [0,16)      : per-batch cumsum + frame->phoneme idx table
//  [16,1040)   : emb f32 -> bf16 cast (2 short8 per thread)
//  [1040,1424) : Wall fragments (6 slabs: dp taps 0-2, f0 taps 0-2)
//  [1424,1520) : Bs2 fragments (dp_w2, K=768)
__global__ __launch_bounds__(256)
void prep_kernel(const float* __restrict__ emb, const int* __restrict__ dur,
                 const float* __restrict__ dp_w1, const float* __restrict__ dp_w2,
                 const float* __restrict__ f0_w1,
                 unsigned short* __restrict__ emb_bf, int* __restrict__ idxarr,
                 unsigned short* __restrict__ Ball, unsigned short* __restrict__ Bs2) {
    const int bid = blockIdx.x, t = threadIdx.x;
    if (bid < 16) {
        __shared__ int cs[NS];
        __shared__ int wsum[4];
        int b = bid, w = t >> 6, lane = t & 63;
        int v0 = dur[b * NS + t * 2], v1 = dur[b * NS + t * 2 + 1];
        int incl = v0 + v1;
        for (int off = 1; off < 64; off <<= 1) {
            int n = __shfl_up(incl, off, 64);
            if (lane >= off) incl += n;
        }
        if (lane == 63) wsum[w] = incl;
        __syncthreads();
        int pre = 0;
        #pragma unroll
        for (int i = 0; i < 4; ++i) if (i < w) pre += wsum[i];
        incl += pre;
        cs[t * 2] = incl - v1;
        cs[t * 2 + 1] = incl;
        __syncthreads();
        int total = cs[NS - 1];
        for (int f = t; f < NT; f += 256) {
            int lo = 0, hi = NS;
            while (lo < hi) {
                int mid = (lo + hi) >> 1;
                if (cs[mid] <= f) lo = mid + 1; else hi = mid;
            }
            idxarr[b * NT + f] = (f < total) ? (lo < NS ? lo : NS - 1) : -1;
        }
    } else if (bid < 1040) {
        int i0 = (bid - 16) * 256 + t;     // short8 index; 2 per thread
        #pragma unroll
        for (int rep = 0; rep < 2; ++rep) {
            int i = i0 + rep * 262144;
            const float4* p = (const float4*)(emb + (size_t)i * 8);
            float4 a0 = p[0], a1 = p[1];
            short8 o;
            o[0] = (short)f2bf(a0.x); o[1] = (short)f2bf(a0.y);
            o[2] = (short)f2bf(a0.z); o[3] = (short)f2bf(a0.w);
            o[4] = (short)f2bf(a1.x); o[5] = (short)f2bf(a1.y);
            o[6] = (short)f2bf(a1.z); o[7] = (short)f2bf(a1.w);
            *(short8*)(emb_bf + (size_t)i * 8) = o;
        }
    } else if (bid < 1424) {
        int gidx8 = (bid - 1040) * 256 + t;
        int q = gidx8 >> 14;
        int r8 = gidx8 & 16383;
        int l  = r8 & 63;
        int s2 = (r8 >> 6) & 1;
        int nf = (r8 >> 7) & 3;
        int w  = (r8 >> 9) & 3;
        int st = r8 >> 11;                  // [0,8)
        int k0  = st * 64 + s2 * 32 + ((l >> 4) << 3);
        int col = w * 64 + nf * 16 + (l & 15);
        int tap = q < 3 ? q : q - 3;
        const float* srcw = q < 3 ? dp_w1 : f0_w1;
        const float* sp = srcw + (size_t)(col * 512 + k0) * 3 + tap;
        short8 o;
        #pragma unroll
        for (int e = 0; e < 8; ++e) o[e] = (short)f2bf(sp[e * 3]);
        *(short8*)(Ball + (size_t)q * 131072 + (size_t)r8 * 8) = o;
    } else {
        int r8 = (bid - 1424) * 256 + t;
        int l  = r8 & 63;
        int s2 = (r8 >> 6) & 1;
        int nf = (r8 >> 7) & 3;
        int w  = (r8 >> 9) & 3;
        int st = r8 >> 11;                  // [0,12)
        int k0  = st * 64 + s2 * 32 + ((l >> 4) << 3);
        int col = w * 64 + nf * 16 + (l & 15);
        int i0  = k0 & 255;
        int ko  = k0 >> 8;
        const float* sp = dp_w2 + (size_t)(col * 256 + i0) * 3 + ko;
        short8 o;
        #pragma unroll
        for (int e = 0; e < 8; ++e) o[e] = (short)f2bf(sp[e * 3]);
        *(short8*)(Bs2 + (size_t)r8 * 8) = o;
    }
}

// ---------------------------------------------------------------------------
// Merged compute+stream kernel with ROLE INTERLEAVING (3:4 per chunk of 7):
//  gemm role: G[q] = emb_bf (8192x512) x Wall[q] (512x256)
//  up role  : exact f32 copy of emb rows per frame
// Interleaved bid->role so every dispatch wave co-schedules MFMA-bound and
// store-bound blocks on each CU (m114 overlap needs co-residency from start).
__global__ __launch_bounds__(256, 3)
void guw_kernel(const float* __restrict__ emb,
                const unsigned short* __restrict__ emb_bf,
                const int* __restrict__ idxarr,
                const unsigned short* __restrict__ Ball,
                unsigned short* __restrict__ G, float* __restrict__ up) {
    constexpr int NSTEP = 8;
    constexpr int BUFS = 64 * 64;
    __shared__ unsigned short smem[64 * 256];   // gemm: 2 A-bufs | H tile; up: il

    const int t = threadIdx.x;
    const int c = blockIdx.x / 7, r = blockIdx.x % 7;

    if (r < 3) {
        const int gb = c * 3 + r;           // gemm block [0,768)
        const int q = gb % 6;
        const int m0 = (gb / 6) * 64;
        const int w = t >> 6, l = t & 63, llo = l & 15, lhi = l >> 4;
        const int arow = t >> 2, sub = t & 3;
        const unsigned short* Bq = Ball + (size_t)q * 131072;
        unsigned short* Gq = G + (size_t)q * GSLAB;

        f32x4 acc[4][4];
        #pragma unroll
        for (int i = 0; i < 4; ++i)
            #pragma unroll
            for (int j = 0; j < 4; ++j) acc[i][j] = (f32x4){0.f, 0.f, 0.f, 0.f};

        short8 a[2];
        short8 b0[8], b1[8];

        auto stageA = [&](int st) {
            const unsigned short* p =
                emb_bf + (size_t)(m0 + arow) * 512 + st * 64 + sub * 16;
            a[0] = *(const short8*)p;
            a[1] = *(const short8*)(p + 8);
        };
        auto dsWriteA = [&](int st) {
            int buf = (st & 1) * BUFS;
            *(short8*)&smem[buf + arow * 64 + (((sub * 2 + 0) ^ (arow & 7)) << 3)] = a[0];
            *(short8*)&smem[buf + arow * 64 + (((sub * 2 + 1) ^ (arow & 7)) << 3)] = a[1];
        };
        auto loadB = [&](int st, short8* bb) {
            const unsigned short* base = Bq + ((size_t)(st * 4 + w) * 8) * 512 + l * 8;
            #pragma unroll
            for (int s = 0; s < 2; ++s)
                #pragma unroll
                for (int nf = 0; nf < 4; ++nf)
                    bb[s * 4 + nf] = *(const short8*)(base + (nf * 2 + s) * 512);
        };
        auto mfmaPhase = [&](int buf, short8* bc) {
            #pragma unroll
            for (int s = 0; s < 2; ++s)
                #pragma unroll
                for (int mf = 0; mf < 4; ++mf) {
                    int row = mf * 16 + llo;
                    short8 af = *(const short8*)&smem[buf + row * 64 +
                                                     ((((s << 2) | lhi) ^ (row & 7)) << 3)];
                    #pragma unroll
                    for (int nf = 0; nf < 4; ++nf)
                        acc[mf][nf] = __builtin_amdgcn_mfma_f32_16x16x32_bf16(
                            af, bc[s * 4 + nf], acc[mf][nf], 0, 0, 0);
                }
        };

        stageA(0);
        dsWriteA(0);
        stageA(1);
        loadB(0, b0);
        __syncthreads();
        for (int st = 0; st < NSTEP; st += 2) {
            loadB(st + 1, b1);
            dsWriteA(st + 1);
            if (st + 2 < NSTEP) stageA(st + 2);
            mfmaPhase(0, b0);
            __syncthreads();
            if (st + 2 < NSTEP) {
                loadB(st + 2, b0);
                dsWriteA(st + 2);
            }
            if (st + 3 < NSTEP) stageA(st + 3);
            mfmaPhase(BUFS, b1);
            __syncthreads();
        }

        unsigned short* H = smem;
        #pragma unroll
        for (int nf = 0; nf < 4; ++nf) {
            int col = w * 64 + nf * 16 + llo;
            #pragma unroll
            for (int mf = 0; mf < 4; ++mf)
                #pragma unroll
                for (int r2 = 0; r2 < 4; ++r2) {
                    int row = mf * 16 + lhi * 4 + r2;
                    H[row * 256 + ((((col >> 2) ^ (row & 15)) << 2) | (col & 3))] =
                        f2bf(acc[mf][nf][r2]);
                }
        }
        __syncthreads();
        #pragma unroll
        for (int it = 0; it < 16; ++it) {
            int lin = it * 256 + t;
            int row = lin >> 6, g = lin & 63;
            us4 hv = *(const us4*)&H[row * 256 + ((g ^ (row & 15)) << 2)];
            *(us4*)&Gq[(size_t)(m0 + row) * 256 + g * 4] = hv;
        }
    } else {
        // --- up-writer: 64 frames per block, exact f32 copy (0 if masked) ---
        int* il = (int*)smem;
        const int ub = c * 4 + (r - 3);     // up block [0,1024)
        const int row0 = ub * 64;
        const int b = row0 >> 12;
        if (t < 64) il[t] = idxarr[row0 + t];
        __syncthreads();
        for (int cc = t; cc < 64 * 128; cc += 256) {
            int rr = cc >> 7, j = cc & 127;
            int ix = il[rr];
            float4 v = make_float4(0.f, 0.f, 0.f, 0.f);
            if (ix >= 0)
                v = ((const float4*)(emb + ((size_t)(b * NS + ix)) * IND0))[j];
            ((float4*)(up + (size_t)(row0 + rr) * IND0))[j] = v;
        }
    }
}

// ---------------------------------------------------------------------------
// f0 combine: sum 3 G rows (slabs 3-5) + bias + relu + LN + head dot -> pf0.
__global__ __launch_bounds__(256, 4)
void f0c_kernel(const int* __restrict__ idxarr,
                const unsigned short* __restrict__ G,
                const float* __restrict__ f0_b1, const float* __restrict__ f0_g1,
                const float* __restrict__ f0_be1, const float* __restrict__ f0_w2,
                const float* __restrict__ f0_b2, float* __restrict__ pf0) {
    __shared__ int il[66];
    const int t = threadIdx.x;
    const int row0 = blockIdx.x * 64;
    const int b = row0 >> 12, t0 = row0 & (NT - 1);

    for (int j = t; j < 66; j += 256) {
        int tf = t0 + j - 1;
        il[j] = (tf >= 0 && tf < NT) ? idxarr[b * NT + tf] : -1;
    }
    __syncthreads();

    const unsigned short* Gf = G + (size_t)3 * GSLAB;
    int r = t >> 2, jj = t & 3;
    int grow = row0 + r;
    f32x4 v[16];
    #pragma unroll
    for (int c = 0; c < 16; ++c) v[c] = (f32x4){0.f, 0.f, 0.f, 0.f};
    #pragma unroll
    for (int k = 0; k < 3; ++k) {
        int ix = il[r + k];
        if (ix >= 0) {
            const unsigned short* Gr = Gf + (size_t)k * GSLAB
                                     + (size_t)(b * NS + ix) * 256 + jj * 64;
            #pragma unroll
            for (int c = 0; c < 16; ++c) {
                us4 hv = *(const us4*)(Gr + c * 4);
                v[c][0] += bf2f(hv[0]); v[c][1] += bf2f(hv[1]);
                v[c][2] += bf2f(hv[2]); v[c][3] += bf2f(hv[3]);
            }
        }
    }
    float sum = 0.f, sq = 0.f;
    #pragma unroll
    for (int c = 0; c < 16; ++c) {
        float4 bv = *(const float4*)&f0_b1[jj * 64 + c * 4];
        #pragma unroll
        for (int e = 0; e < 4; ++e) {
            float x = v[c][e] + ((const float*)&bv)[e];
            x = x > 0.f ? x : 0.f;
            v[c][e] = x;
            sum += x; sq += x * x;
        }
    }
    sum += __shfl_xor(sum, 1); sq += __shfl_xor(sq, 1);
    sum += __shfl_xor(sum, 2); sq += __shfl_xor(sq, 2);
    float mean = sum * (1.f / 256.f);
    float rs = rsqrtf(sq * (1.f / 256.f) - mean * mean + 1e-5f);
    float part = 0.f;
    #pragma unroll
    for (int c = 0; c < 16; ++c) {
        float4 gv = *(const float4*)&f0_g1[jj * 64 + c * 4];
        float4 be = *(const float4*)&f0_be1[jj * 64 + c * 4];
        float4 wf = *(const float4*)&f0_w2[jj * 64 + c * 4];
        part += ((v[c][0] - mean) * rs * gv.x + be.x) * wf.x;
        part += ((v[c][1] - mean) * rs * gv.y + be.y) * wf.y;
        part += ((v[c][2] - mean) * rs * gv.z + be.z) * wf.z;
        part += ((v[c][3] - mean) * rs * gv.w + be.w) * wf.w;
    }
    part += __shfl_xor(part, 1);
    part += __shfl_xor(part, 2);
    if (jj == 0) pf0[grow] = part + f0_b2[0];
}

// ---------------------------------------------------------------------------
// Fused dp chain: build 34 h1 rows in LDS from G slabs 0-2 (combine+LN),
// one barrier, then barrier-free K loop (A-resident, B reg ping-pong) +
// LN + dur head. 32 output rows per block.
__global__ __launch_bounds__(256, 4)
void dpf_kernel(const unsigned short* __restrict__ G,
                const float* __restrict__ dp_b1, const float* __restrict__ dp_g1,
                const float* __restrict__ dp_be1,
                const unsigned short* __restrict__ Bs2,
                const float* __restrict__ bias2, const float* __restrict__ gamma2,
                const float* __restrict__ beta2,
                const float* __restrict__ wfin, const float* __restrict__ bfin,
                float* __restrict__ pdur) {
    constexpr int NSTEP = 12;
    __shared__ unsigned short A[34 * 256];
    __shared__ unsigned short H[32 * 256];

    const int t = threadIdx.x;
    const int m0 = blockIdx.x * 32;
    const int w = t >> 6, l = t & 63, llo = l & 15, lhi = l >> 4;

    {
        int sub = t & 7;
        for (int j = t >> 3; j < 34; j += 32) {
            int sm = (m0 & (NS - 1)) - 1 + j;
            bool rowv = (sm >= 0 && sm < NS);
            int m = m0 - 1 + j;
            f32x4 v[8];
            #pragma unroll
            for (int c = 0; c < 8; ++c) v[c] = (f32x4){0.f, 0.f, 0.f, 0.f};
            if (rowv) {
                #pragma unroll
                for (int k = 0; k < 3; ++k) {
                    int sp = sm + k - 1;
                    if (sp >= 0 && sp < NS) {
                        const unsigned short* Gr = G + (size_t)k * GSLAB
                                                 + (size_t)(m + k - 1) * 256 + sub * 32;
                        #pragma unroll
                        for (int c = 0; c < 8; ++c) {
                            us4 hv = *(const us4*)(Gr + c * 4);
                            v[c][0] += bf2f(hv[0]); v[c][1] += bf2f(hv[1]);
                            v[c][2] += bf2f(hv[2]); v[c][3] += bf2f(hv[3]);
                        }
                    }
                }
            }
            float sum = 0.f, sq = 0.f;
            #pragma unroll
            for (int c = 0; c < 8; ++c) {
                float4 bv = *(const float4*)&dp_b1[sub * 32 + c * 4];
                #pragma unroll
                for (int e = 0; e < 4; ++e) {
                    float x = v[c][e] + ((const float*)&bv)[e];
                    x = x > 0.f ? x : 0.f;
                    v[c][e] = x; sum += x; sq += x * x;
                }
            }
            #pragma unroll
            for (int off = 4; off >= 1; off >>= 1) {
                sum += __shfl_xor(sum, off);
                sq  += __shfl_xor(sq, off);
            }
            float mean = sum * (1.f / 256.f);
            float rs = rsqrtf(sq * (1.f / 256.f) - mean * mean + 1e-5f);
            #pragma unroll
            for (int cc = 0; cc < 4; ++cc) {
                int ch = sub * 4 + cc;
                float4 g0 = *(const float4*)&dp_g1[ch * 8];
                float4 g1 = *(const float4*)&dp_g1[ch * 8 + 4];
                float4 e0 = *(const float4*)&dp_be1[ch * 8];
                float4 e1 = *(const float4*)&dp_be1[ch * 8 + 4];
                short8 o;
                if (rowv) {
                    f32x4 lo = v[cc * 2], hi = v[cc * 2 + 1];
                    o[0] = (short)f2bf((lo[0] - mean) * rs * g0.x + e0.x);
                    o[1] = (short)f2bf((lo[1] - mean) * rs * g0.y + e0.y);
                    o[2] = (short)f2bf((lo[2] - mean) * rs * g0.z + e0.z);
                    o[3] = (short)f2bf((lo[3] - mean) * rs * g0.w + e0.w);
                    o[4] = (short)f2bf((hi[0] - mean) * rs * g1.x + e1.x);
                    o[5] = (short)f2bf((hi[1] - mean) * rs * g1.y + e1.y);
                    o[6] = (short)f2bf((hi[2] - mean) * rs * g1.z + e1.z);
                    o[7] = (short)f2bf((hi[3] - mean) * rs * g1.w + e1.w);
                } else {
                    o = short8{0,0,0,0,0,0,0,0};
                }
                *(short8*)&A[j * 256 + ((ch ^ (j & 7)) << 3)] = o;
            }
        }
    }
    __syncthreads();

    f32x4 acc[2][4];
    #pragma unroll
    for (int i = 0; i < 2; ++i)
        #pragma unroll
        for (int j = 0; j < 4; ++j) acc[i][j] = (f32x4){0.f, 0.f, 0.f, 0.f};

    short8 b0[8], b1[8];
    auto loadB = [&](int st, short8* bb) {
        const unsigned short* base = Bs2 + ((size_t)(st * 4 + w) * 8) * 512 + l * 8;
        #pragma unroll
        for (int s = 0; s < 2; ++s)
            #pragma unroll
            for (int nf = 0; nf < 4; ++nf)
                bb[s * 4 + nf] = *(const short8*)(base + (nf * 2 + s) * 512);
    };
    auto mfmaPhase = [&](int st, short8* bc) {
        int ko = st >> 2;
        int cb = (st & 3) << 3;
        #pragma unroll
        for (int s = 0; s < 2; ++s)
            #pragma unroll
            for (int mf = 0; mf < 2; ++mf) {
                int jr = mf * 16 + llo + ko;
                int ch = cb + ((s << 2) | lhi);
                short8 af = *(const short8*)&A[jr * 256 + ((ch ^ (jr & 7)) << 3)];
                #pragma unroll
                for (int nf = 0; nf < 4; ++nf)
                    acc[mf][nf] = __builtin_amdgcn_mfma_f32_16x16x32_bf16(
                        af, bc[s * 4 + nf], acc[mf][nf], 0, 0, 0);
            }
    };

    loadB(0, b0);
    for (int st = 0; st < NSTEP; st += 2) {
        loadB(st + 1, b1);
        mfmaPhase(st, b0);
        if (st + 2 < NSTEP) loadB(st + 2, b0);
        mfmaPhase(st + 1, b1);
    }

    #pragma unroll
    for (int nf = 0; nf < 4; ++nf) {
        int col = w * 64 + nf * 16 + llo;
        float bv = bias2[col];
        #pragma unroll
        for (int mf = 0; mf < 2; ++mf)
            #pragma unroll
            for (int r = 0; r < 4; ++r) {
                int row = mf * 16 + lhi * 4 + r;
                float x = acc[mf][nf][r] + bv;
                x = x > 0.f ? x : 0.f;
                H[row * 256 + ((((col >> 2) ^ (row & 15)) << 2) | (col & 3))] = f2bf(x);
            }
    }
    __syncthreads();

    int row = t >> 3, jj = t & 7;
    const unsigned short* Hr = H + row * 256;
    int rx = row & 15;
    float sum = 0.f, sq = 0.f;
    #pragma unroll
    for (int c4 = 0; c4 < 8; ++c4) {
        int g = jj * 8 + c4;
        us4 hv = *(const us4*)&Hr[(g ^ rx) << 2];
        #pragma unroll
        for (int e = 0; e < 4; ++e) { float f = bf2f(hv[e]); sum += f; sq += f * f; }
    }
    #pragma unroll
    for (int off = 4; off >= 1; off >>= 1) {
        sum += __shfl_xor(sum, off);
        sq  += __shfl_xor(sq, off);
    }
    float mean = sum * (1.f / 256.f);
    float rs = rsqrtf(sq * (1.f / 256.f) - mean * mean + 1e-5f);
    float part = 0.f;
    #pragma unroll
    for (int c4 = 0; c4 < 8; ++c4) {
        int g = jj * 8 + c4;
        us4 hv = *(const us4*)&Hr[(g ^ rx) << 2];
        float4 gv = *(const float4*)&gamma2[g * 4];
        float4 bv = *(const float4*)&beta2[g * 4];
        float4 wv = *(const float4*)&wfin[g * 4];
        part += ((bf2f(hv[0]) - mean) * rs * gv.x + bv.x) * wv.x;
        part += ((bf2f(hv[1]) - mean) * rs * gv.y + bv.y) * wv.y;
        part += ((bf2f(hv[2]) - mean) * rs * gv.z + bv.z) * wv.z;
        part += ((bf2f(hv[3]) - mean) * rs * gv.w + bv.w) * wv.w;
    }
    #pragma unroll
    for (int off = 4; off >= 1; off >>= 1) part += __shfl_xor(part, off);
    if (jj == 0) {
        float r = part + bfin[0];
        r = expf(r); r = r > 1.f ? r : 1.f;
        pdur[m0 + row] = r;
    }
}

// ---------------------------------------------------------------------------
extern "C" void kernel_launch(void* const* d_in, const int* in_sizes, int n_in,
                              void* d_out, int out_size, void* d_ws, size_t ws_size,
                              hipStream_t stream) {
    const float* emb    = (const float*)d_in[0];
    const int*   dur    = (const int*)  d_in[1];
    const float* dp_w1  = (const float*)d_in[2];
    const float* dp_b1  = (const float*)d_in[3];
    const float* dp_g1  = (const float*)d_in[4];
    const float* dp_be1 = (const float*)d_in[5];
    const float* dp_w2  = (const float*)d_in[6];
    const float* dp_b2  = (const float*)d_in[7];
    const float* dp_g2  = (const float*)d_in[8];
    const float* dp_be2 = (const float*)d_in[9];
    const float* dp_w3  = (const float*)d_in[10];
    const float* dp_b3  = (const float*)d_in[11];
    const float* f0_w1  = (const float*)d_in[12];
    const float* f0_b1  = (const float*)d_in[13];
    const float* f0_g1  = (const float*)d_in[14];
    const float* f0_be1 = (const float*)d_in[15];
    const float* f0_w2  = (const float*)d_in[16];
    const float* f0_b2  = (const float*)d_in[17];

    float* up   = (float*)d_out;                       // (16, 4096, 512)
    float* pdur = up + (size_t)NB * NT * IND0;         // (16, 512)
    float* pf0  = pdur + NB * NS;                      // (16, 4096)

    char* ws = (char*)d_ws;
    int*            idxarr = (int*)(ws);                          // 256 KB
    unsigned short* Ball   = (unsigned short*)(ws + 262144);      // 1.5 MB
    unsigned short* Bs2    = (unsigned short*)(ws + 1835008);     // 384 KB
    unsigned short* emb_bf = (unsigned short*)(ws + 6422528);     // 8 MB
    unsigned short* G      = (unsigned short*)(ws + 14811136);    // 24 MB

    prep_kernel<<<1520, 256, 0, stream>>>(emb, dur, dp_w1, dp_w2, f0_w1,
                                          emb_bf, idxarr, Ball, Bs2);

    // GEMM + up-writer, role-interleaved (3:4 per 7-block chunk)
    guw_kernel<<<NGEMM + NUP, 256, 0, stream>>>(
        emb, emb_bf, idxarr, Ball, G, up);

    // f0 combine (reads G slabs 3-5)
    f0c_kernel<<<NB * NT / 64, 256, 0, stream>>>(
        idxarr, G, f0_b1, f0_g1, f0_be1, f0_w2, f0_b2, pf0);

    // fused dp chain (reads G slabs 0-2) -> pdur
    dpf_kernel<<<NROW / 32, 256, 0, stream>>>(
        G, dp_b1, dp_g1, dp_be1, Bs2, dp_b2, dp_g2, dp_be2,
        dp_w3, dp_b3, pdur);
}

// Round 17
// 118.556 us; speedup vs baseline: 1.0313x; 1.0007x over previous
//
#include <hip/hip_runtime.h>
#include <math.h>

typedef __attribute__((ext_vector_type(8))) short short8;
typedef __attribute__((ext_vector_type(4))) float f32x4;
typedef __attribute__((ext_vector_type(4))) unsigned short us4;

constexpr int NB = 16, NS = 512, NT = 4096, IND0 = 512;
constexpr int NROW = NB * NS;        // 8192 phoneme rows
constexpr int GSLAB = NROW * 256;    // elements per G slab
constexpr int NGEMM = (NROW / 64) * 6;   // 768 gemm blocks
constexpr int NUP = NB * NT / 64;        // 1024 up-writer blocks

__device__ __forceinline__ unsigned short f2bf(float f) {
    __bf16 h = (__bf16)f;
    return __builtin_bit_cast(unsigned short, h);
}
__device__ __forceinline__ float bf2f(unsigned short h) {
    return __uint_as_float(((unsigned)h) << 16);
}

// ---------------------------------------------------------------------------
// Merged prep kernel (vectorized writers):
//  [0,16)      : per-batch cumsum + frame->phoneme idx table
//  [16,1040)   : emb f32 -> bf16 cast (2 short8 per thread)
//  [1040,1424) : Wall fragments (6 slabs: dp taps 0-2, f0 taps 0-2)
//  [1424,1520) : Bs2 fragments (dp_w2, K=768)
__global__ __launch_bounds__(256)
void prep_kernel(const float* __restrict__ emb, const int* __restrict__ dur,
                 const float* __restrict__ dp_w1, const float* __restrict__ dp_w2,
                 const float* __restrict__ f0_w1,
                 unsigned short* __restrict__ emb_bf, int* __restrict__ idxarr,
                 unsigned short* __restrict__ Ball, unsigned short* __restrict__ Bs2) {
    const int bid = blockIdx.x, t = threadIdx.x;
    if (bid < 16) {
        __shared__ int cs[NS];
        __shared__ int wsum[4];
        int b = bid, w = t >> 6, lane = t & 63;
        int v0 = dur[b * NS + t * 2], v1 = dur[b * NS + t * 2 + 1];
        int incl = v0 + v1;
        for (int off = 1; off < 64; off <<= 1) {
            int n = __shfl_up(incl, off, 64);
            if (lane >= off) incl += n;
        }
        if (lane == 63) wsum[w] = incl;
        __syncthreads();
        int pre = 0;
        #pragma unroll
        for (int i = 0; i < 4; ++i) if (i < w) pre += wsum[i];
        incl += pre;
        cs[t * 2] = incl - v1;
        cs[t * 2 + 1] = incl;
        __syncthreads();
        int total = cs[NS - 1];
        for (int f = t; f < NT; f += 256) {
            int lo = 0, hi = NS;
            while (lo < hi) {
                int mid = (lo + hi) >> 1;
                if (cs[mid] <= f) lo = mid + 1; else hi = mid;
            }
            idxarr[b * NT + f] = (f < total) ? (lo < NS ? lo : NS - 1) : -1;
        }
    } else if (bid < 1040) {
        int i0 = (bid - 16) * 256 + t;     // short8 index; 2 per thread
        #pragma unroll
        for (int rep = 0; rep < 2; ++rep) {
            int i = i0 + rep * 262144;
            const float4* p = (const float4*)(emb + (size_t)i * 8);
            float4 a0 = p[0], a1 = p[1];
            short8 o;
            o[0] = (short)f2bf(a0.x); o[1] = (short)f2bf(a0.y);
            o[2] = (short)f2bf(a0.z); o[3] = (short)f2bf(a0.w);
            o[4] = (short)f2bf(a1.x); o[5] = (short)f2bf(a1.y);
            o[6] = (short)f2bf(a1.z); o[7] = (short)f2bf(a1.w);
            *(short8*)(emb_bf + (size_t)i * 8) = o;
        }
    } else if (bid < 1424) {
        int gidx8 = (bid - 1040) * 256 + t;
        int q = gidx8 >> 14;
        int r8 = gidx8 & 16383;
        int l  = r8 & 63;
        int s2 = (r8 >> 6) & 1;
        int nf = (r8 >> 7) & 3;
        int w  = (r8 >> 9) & 3;
        int st = r8 >> 11;                  // [0,8)
        int k0  = st * 64 + s2 * 32 + ((l >> 4) << 3);
        int col = w * 64 + nf * 16 + (l & 15);
        int tap = q < 3 ? q : q - 3;
        const float* srcw = q < 3 ? dp_w1 : f0_w1;
        const float* sp = srcw + (size_t)(col * 512 + k0) * 3 + tap;
        short8 o;
        #pragma unroll
        for (int e = 0; e < 8; ++e) o[e] = (short)f2bf(sp[e * 3]);
        *(short8*)(Ball + (size_t)q * 131072 + (size_t)r8 * 8) = o;
    } else {
        int r8 = (bid - 1424) * 256 + t;
        int l  = r8 & 63;
        int s2 = (r8 >> 6) & 1;
        int nf = (r8 >> 7) & 3;
        int w  = (r8 >> 9) & 3;
        int st = r8 >> 11;                  // [0,12)
        int k0  = st * 64 + s2 * 32 + ((l >> 4) << 3);
        int col = w * 64 + nf * 16 + (l & 15);
        int i0  = k0 & 255;
        int ko  = k0 >> 8;
        const float* sp = dp_w2 + (size_t)(col * 256 + i0) * 3 + ko;
        short8 o;
        #pragma unroll
        for (int e = 0; e < 8; ++e) o[e] = (short)f2bf(sp[e * 3]);
        *(short8*)(Bs2 + (size_t)r8 * 8) = o;
    }
}

// ---------------------------------------------------------------------------
// Merged compute+stream kernel with ROLE INTERLEAVING (3:4 per chunk of 7):
//  gemm role: G[q] = emb_bf (8192x512) x Wall[q] (512x256)
//  up role  : exact f32 copy of emb rows per frame
__global__ __launch_bounds__(256, 3)
void guw_kernel(const float* __restrict__ emb,
                const unsigned short* __restrict__ emb_bf,
                const int* __restrict__ idxarr,
                const unsigned short* __restrict__ Ball,
                unsigned short* __restrict__ G, float* __restrict__ up) {
    constexpr int NSTEP = 8;
    constexpr int BUFS = 64 * 64;
    __shared__ unsigned short smem[64 * 256];   // gemm: 2 A-bufs | H tile; up: il

    const int t = threadIdx.x;
    const int c = blockIdx.x / 7, r = blockIdx.x % 7;

    if (r < 3) {
        const int gb = c * 3 + r;           // gemm block [0,768)
        const int q = gb % 6;
        const int m0 = (gb / 6) * 64;
        const int w = t >> 6, l = t & 63, llo = l & 15, lhi = l >> 4;
        const int arow = t >> 2, sub = t & 3;
        const unsigned short* Bq = Ball + (size_t)q * 131072;
        unsigned short* Gq = G + (size_t)q * GSLAB;

        f32x4 acc[4][4];
        #pragma unroll
        for (int i = 0; i < 4; ++i)
            #pragma unroll
            for (int j = 0; j < 4; ++j) acc[i][j] = (f32x4){0.f, 0.f, 0.f, 0.f};

        short8 a[2];
        short8 b0[8], b1[8];

        auto stageA = [&](int st) {
            const unsigned short* p =
                emb_bf + (size_t)(m0 + arow) * 512 + st * 64 + sub * 16;
            a[0] = *(const short8*)p;
            a[1] = *(const short8*)(p + 8);
        };
        auto dsWriteA = [&](int st) {
            int buf = (st & 1) * BUFS;
            *(short8*)&smem[buf + arow * 64 + (((sub * 2 + 0) ^ (arow & 7)) << 3)] = a[0];
            *(short8*)&smem[buf + arow * 64 + (((sub * 2 + 1) ^ (arow & 7)) << 3)] = a[1];
        };
        auto loadB = [&](int st, short8* bb) {
            const unsigned short* base = Bq + ((size_t)(st * 4 + w) * 8) * 512 + l * 8;
            #pragma unroll
            for (int s = 0; s < 2; ++s)
                #pragma unroll
                for (int nf = 0; nf < 4; ++nf)
                    bb[s * 4 + nf] = *(const short8*)(base + (nf * 2 + s) * 512);
        };
        auto mfmaPhase = [&](int buf, short8* bc) {
            #pragma unroll
            for (int s = 0; s < 2; ++s)
                #pragma unroll
                for (int mf = 0; mf < 4; ++mf) {
                    int row = mf * 16 + llo;
                    short8 af = *(const short8*)&smem[buf + row * 64 +
                                                     ((((s << 2) | lhi) ^ (row & 7)) << 3)];
                    #pragma unroll
                    for (int nf = 0; nf < 4; ++nf)
                        acc[mf][nf] = __builtin_amdgcn_mfma_f32_16x16x32_bf16(
                            af, bc[s * 4 + nf], acc[mf][nf], 0, 0, 0);
                }
        };

        stageA(0);
        dsWriteA(0);
        stageA(1);
        loadB(0, b0);
        __syncthreads();
        for (int st = 0; st < NSTEP; st += 2) {
            loadB(st + 1, b1);
            dsWriteA(st + 1);
            if (st + 2 < NSTEP) stageA(st + 2);
            mfmaPhase(0, b0);
            __syncthreads();
            if (st + 2 < NSTEP) {
                loadB(st + 2, b0);
                dsWriteA(st + 2);
            }
            if (st + 3 < NSTEP) stageA(st + 3);
            mfmaPhase(BUFS, b1);
            __syncthreads();
        }

        unsigned short* H = smem;
        #pragma unroll
        for (int nf = 0; nf < 4; ++nf) {
            int col = w * 64 + nf * 16 + llo;
            #pragma unroll
            for (int mf = 0; mf < 4; ++mf)
                #pragma unroll
                for (int r2 = 0; r2 < 4; ++r2) {
                    int row = mf * 16 + lhi * 4 + r2;
                    H[row * 256 + ((((col >> 2) ^ (row & 15)) << 2) | (col & 3))] =
                        f2bf(acc[mf][nf][r2]);
                }
        }
        __syncthreads();
        #pragma unroll
        for (int it = 0; it < 16; ++it) {
            int lin = it * 256 + t;
            int row = lin >> 6, g = lin & 63;
            us4 hv = *(const us4*)&H[row * 256 + ((g ^ (row & 15)) << 2)];
            *(us4*)&Gq[(size_t)(m0 + row) * 256 + g * 4] = hv;
        }
    } else {
        // --- up-writer: 64 frames per block, exact f32 copy (0 if masked) ---
        int* il = (int*)smem;
        const int ub = c * 4 + (r - 3);     // up block [0,1024)
        const int row0 = ub * 64;
        const int b = row0 >> 12;
        if (t < 64) il[t] = idxarr[row0 + t];
        __syncthreads();
        for (int cc = t; cc < 64 * 128; cc += 256) {
            int rr = cc >> 7, j = cc & 127;
            int ix = il[rr];
            float4 v = make_float4(0.f, 0.f, 0.f, 0.f);
            if (ix >= 0)
                v = ((const float4*)(emb + ((size_t)(b * NS + ix)) * IND0))[j];
            ((float4*)(up + (size_t)(row0 + rr) * IND0))[j] = v;
        }
    }
}

// ---------------------------------------------------------------------------
// f0 combine: sum 3 G rows (slabs 3-5) + bias + relu + LN + head dot -> pf0.
__global__ __launch_bounds__(256, 4)
void f0c_kernel(const int* __restrict__ idxarr,
                const unsigned short* __restrict__ G,
                const float* __restrict__ f0_b1, const float* __restrict__ f0_g1,
                const float* __restrict__ f0_be1, const float* __restrict__ f0_w2,
                const float* __restrict__ f0_b2, float* __restrict__ pf0) {
    __shared__ int il[66];
    const int t = threadIdx.x;
    const int row0 = blockIdx.x * 64;
    const int b = row0 >> 12, t0 = row0 & (NT - 1);

    for (int j = t; j < 66; j += 256) {
        int tf = t0 + j - 1;
        il[j] = (tf >= 0 && tf < NT) ? idxarr[b * NT + tf] : -1;
    }
    __syncthreads();

    const unsigned short* Gf = G + (size_t)3 * GSLAB;
    int r = t >> 2, jj = t & 3;
    int grow = row0 + r;
    f32x4 v[16];
    #pragma unroll
    for (int c = 0; c < 16; ++c) v[c] = (f32x4){0.f, 0.f, 0.f, 0.f};
    #pragma unroll
    for (int k = 0; k < 3; ++k) {
        int ix = il[r + k];
        if (ix >= 0) {
            const unsigned short* Gr = Gf + (size_t)k * GSLAB
                                     + (size_t)(b * NS + ix) * 256 + jj * 64;
            #pragma unroll
            for (int c = 0; c < 16; ++c) {
                us4 hv = *(const us4*)(Gr + c * 4);
                v[c][0] += bf2f(hv[0]); v[c][1] += bf2f(hv[1]);
                v[c][2] += bf2f(hv[2]); v[c][3] += bf2f(hv[3]);
            }
        }
    }
    float sum = 0.f, sq = 0.f;
    #pragma unroll
    for (int c = 0; c < 16; ++c) {
        float4 bv = *(const float4*)&f0_b1[jj * 64 + c * 4];
        #pragma unroll
        for (int e = 0; e < 4; ++e) {
            float x = v[c][e] + ((const float*)&bv)[e];
            x = x > 0.f ? x : 0.f;
            v[c][e] = x;
            sum += x; sq += x * x;
        }
    }
    sum += __shfl_xor(sum, 1); sq += __shfl_xor(sq, 1);
    sum += __shfl_xor(sum, 2); sq += __shfl_xor(sq, 2);
    float mean = sum * (1.f / 256.f);
    float rs = rsqrtf(sq * (1.f / 256.f) - mean * mean + 1e-5f);
    float part = 0.f;
    #pragma unroll
    for (int c = 0; c < 16; ++c) {
        float4 gv = *(const float4*)&f0_g1[jj * 64 + c * 4];
        float4 be = *(const float4*)&f0_be1[jj * 64 + c * 4];
        float4 wf = *(const float4*)&f0_w2[jj * 64 + c * 4];
        part += ((v[c][0] - mean) * rs * gv.x + be.x) * wf.x;
        part += ((v[c][1] - mean) * rs * gv.y + be.y) * wf.y;
        part += ((v[c][2] - mean) * rs * gv.z + be.z) * wf.z;
        part += ((v[c][3] - mean) * rs * gv.w + be.w) * wf.w;
    }
    part += __shfl_xor(part, 1);
    part += __shfl_xor(part, 2);
    if (jj == 0) pf0[grow] = part + f0_b2[0];
}

// ---------------------------------------------------------------------------
// Fused dp chain: build 34 h1 rows in LDS from G slabs 0-2 (combine+LN),
// one barrier, then barrier-free K loop (A-resident, B reg ping-pong) +
// LN + dur head. 32 output rows per block.
__global__ __launch_bounds__(256, 4)
void dpf_kernel(const unsigned short* __restrict__ G,
                const float* __restrict__ dp_b1, const float* __restrict__ dp_g1,
                const float* __restrict__ dp_be1,
                const unsigned short* __restrict__ Bs2,
                const float* __restrict__ bias2, const float* __restrict__ gamma2,
                const float* __restrict__ beta2,
                const float* __restrict__ wfin, const float* __restrict__ bfin,
                float* __restrict__ pdur) {
    constexpr int NSTEP = 12;
    __shared__ unsigned short A[34 * 256];
    __shared__ unsigned short H[32 * 256];

    const int t = threadIdx.x;
    const int m0 = blockIdx.x * 32;
    const int w = t >> 6, l = t & 63, llo = l & 15, lhi = l >> 4;

    {
        int sub = t & 7;
        for (int j = t >> 3; j < 34; j += 32) {
            int sm = (m0 & (NS - 1)) - 1 + j;
            bool rowv = (sm >= 0 && sm < NS);
            int m = m0 - 1 + j;
            f32x4 v[8];
            #pragma unroll
            for (int c = 0; c < 8; ++c) v[c] = (f32x4){0.f, 0.f, 0.f, 0.f};
            if (rowv) {
                #pragma unroll
                for (int k = 0; k < 3; ++k) {
                    int sp = sm + k - 1;
                    if (sp >= 0 && sp < NS) {
                        const unsigned short* Gr = G + (size_t)k * GSLAB
                                                 + (size_t)(m + k - 1) * 256 + sub * 32;
                        #pragma unroll
                        for (int c = 0; c < 8; ++c) {
                            us4 hv = *(const us4*)(Gr + c * 4);
                            v[c][0] += bf2f(hv[0]); v[c][1] += bf2f(hv[1]);
                            v[c][2] += bf2f(hv[2]); v[c][3] += bf2f(hv[3]);
                        }
                    }
                }
            }
            float sum = 0.f, sq = 0.f;
            #pragma unroll
            for (int c = 0; c < 8; ++c) {
                float4 bv = *(const float4*)&dp_b1[sub * 32 + c * 4];
                #pragma unroll
                for (int e = 0; e < 4; ++e) {
                    float x = v[c][e] + ((const float*)&bv)[e];
                    x = x > 0.f ? x : 0.f;
                    v[c][e] = x; sum += x; sq += x * x;
                }
            }
            #pragma unroll
            for (int off = 4; off >= 1; off >>= 1) {
                sum += __shfl_xor(sum, off);
                sq  += __shfl_xor(sq, off);
            }
            float mean = sum * (1.f / 256.f);
            float rs = rsqrtf(sq * (1.f / 256.f) - mean * mean + 1e-5f);
            #pragma unroll
            for (int cc = 0; cc < 4; ++cc) {
                int ch = sub * 4 + cc;
                float4 g0 = *(const float4*)&dp_g1[ch * 8];
                float4 g1 = *(const float4*)&dp_g1[ch * 8 + 4];
                float4 e0 = *(const float4*)&dp_be1[ch * 8];
                float4 e1 = *(const float4*)&dp_be1[ch * 8 + 4];
                short8 o;
                if (rowv) {
                    f32x4 lo = v[cc * 2], hi = v[cc * 2 + 1];
                    o[0] = (short)f2bf((lo[0] - mean) * rs * g0.x + e0.x);
                    o[1] = (short)f2bf((lo[1] - mean) * rs * g0.y + e0.y);
                    o[2] = (short)f2bf((lo[2] - mean) * rs * g0.z + e0.z);
                    o[3] = (short)f2bf((lo[3] - mean) * rs * g0.w + e0.w);
                    o[4] = (short)f2bf((hi[0] - mean) * rs * g1.x + e1.x);
                    o[5] = (short)f2bf((hi[1] - mean) * rs * g1.y + e1.y);
                    o[6] = (short)f2bf((hi[2] - mean) * rs * g1.z + e1.z);
                    o[7] = (short)f2bf((hi[3] - mean) * rs * g1.w + e1.w);
                } else {
                    o = short8{0,0,0,0,0,0,0,0};
                }
                *(short8*)&A[j * 256 + ((ch ^ (j & 7)) << 3)] = o;
            }
        }
    }
    __syncthreads();

    f32x4 acc[2][4];
    #pragma unroll
    for (int i = 0; i < 2; ++i)
        #pragma unroll
        for (int j = 0; j < 4; ++j) acc[i][j] = (f32x4){0.f, 0.f, 0.f, 0.f};

    short8 b0[8], b1[8];
    auto loadB = [&](int st, short8* bb) {
        const unsigned short* base = Bs2 + ((size_t)(st * 4 + w) * 8) * 512 + l * 8;
        #pragma unroll
        for (int s = 0; s < 2; ++s)
            #pragma unroll
            for (int nf = 0; nf < 4; ++nf)
                bb[s * 4 + nf] = *(const short8*)(base + (nf * 2 + s) * 512);
    };
    auto mfmaPhase = [&](int st, short8* bc) {
        int ko = st >> 2;
        int cb = (st & 3) << 3;
        #pragma unroll
        for (int s = 0; s < 2; ++s)
            #pragma unroll
            for (int mf = 0; mf < 2; ++mf) {
                int jr = mf * 16 + llo + ko;
                int ch = cb + ((s << 2) | lhi);
                short8 af = *(const short8*)&A[jr * 256 + ((ch ^ (jr & 7)) << 3)];
                #pragma unroll
                for (int nf = 0; nf < 4; ++nf)
                    acc[mf][nf] = __builtin_amdgcn_mfma_f32_16x16x32_bf16(
                        af, bc[s * 4 + nf], acc[mf][nf], 0, 0, 0);
            }
    };

    loadB(0, b0);
    for (int st = 0; st < NSTEP; st += 2) {
        loadB(st + 1, b1);
        mfmaPhase(st, b0);
        if (st + 2 < NSTEP) loadB(st + 2, b0);
        mfmaPhase(st + 1, b1);
    }

    #pragma unroll
    for (int nf = 0; nf < 4; ++nf) {
        int col = w * 64 + nf * 16 + llo;
        float bv = bias2[col];
        #pragma unroll
        for (int mf = 0; mf < 2; ++mf)
            #pragma unroll
            for (int r = 0; r < 4; ++r) {
                int row = mf * 16 + lhi * 4 + r;
                float x = acc[mf][nf][r] + bv;
                x = x > 0.f ? x : 0.f;
                H[row * 256 + ((((col >> 2) ^ (row & 15)) << 2) | (col & 3))] = f2bf(x);
            }
    }
    __syncthreads();

    int row = t >> 3, jj = t & 7;
    const unsigned short* Hr = H + row * 256;
    int rx = row & 15;
    float sum = 0.f, sq = 0.f;
    #pragma unroll
    for (int c4 = 0; c4 < 8; ++c4) {
        int g = jj * 8 + c4;
        us4 hv = *(const us4*)&Hr[(g ^ rx) << 2];
        #pragma unroll
        for (int e = 0; e < 4; ++e) { float f = bf2f(hv[e]); sum += f; sq += f * f; }
    }
    #pragma unroll
    for (int off = 4; off >= 1; off >>= 1) {
        sum += __shfl_xor(sum, off);
        sq  += __shfl_xor(sq, off);
    }
    float mean = sum * (1.f / 256.f);
    float rs = rsqrtf(sq * (1.f / 256.f) - mean * mean + 1e-5f);
    float part = 0.f;
    #pragma unroll
    for (int c4 = 0; c4 < 8; ++c4) {
        int g = jj * 8 + c4;
        us4 hv = *(const us4*)&Hr[(g ^ rx) << 2];
        float4 gv = *(const float4*)&gamma2[g * 4];
        float4 bv = *(const float4*)&beta2[g * 4];
        float4 wv = *(const float4*)&wfin[g * 4];
        part += ((bf2f(hv[0]) - mean) * rs * gv.x + bv.x) * wv.x;
        part += ((bf2f(hv[1]) - mean) * rs * gv.y + bv.y) * wv.y;
        part += ((bf2f(hv[2]) - mean) * rs * gv.z + bv.z) * wv.z;
        part += ((bf2f(hv[3]) - mean) * rs * gv.w + bv.w) * wv.w;
    }
    #pragma unroll
    for (int off = 4; off >= 1; off >>= 1) part += __shfl_xor(part, off);
    if (jj == 0) {
        float r = part + bfin[0];
        r = expf(r); r = r > 1.f ? r : 1.f;
        pdur[m0 + row] = r;
    }
}

// ---------------------------------------------------------------------------
extern "C" void kernel_launch(void* const* d_in, const int* in_sizes, int n_in,
                              void* d_out, int out_size, void* d_ws, size_t ws_size,
                              hipStream_t stream) {
    const float* emb    = (const float*)d_in[0];
    const int*   dur    = (const int*)  d_in[1];
    const float* dp_w1  = (const float*)d_in[2];
    const float* dp_b1  = (const float*)d_in[3];
    const float* dp_g1  = (const float*)d_in[4];
    const float* dp_be1 = (const float*)d_in[5];
    const float* dp_w2  = (const float*)d_in[6];
    const float* dp_b2  = (const float*)d_in[7];
    const float* dp_g2  = (const float*)d_in[8];
    const float* dp_be2 = (const float*)d_in[9];
    const float* dp_w3  = (const float*)d_in[10];
    const float* dp_b3  = (const float*)d_in[11];
    const float* f0_w1  = (const float*)d_in[12];
    const float* f0_b1  = (const float*)d_in[13];
    const float* f0_g1  = (const float*)d_in[14];
    const float* f0_be1 = (const float*)d_in[15];
    const float* f0_w2  = (const float*)d_in[16];
    const float* f0_b2  = (const float*)d_in[17];

    float* up   = (float*)d_out;                       // (16, 4096, 512)
    float* pdur = up + (size_t)NB * NT * IND0;         // (16, 512)
    float* pf0  = pdur + NB * NS;                      // (16, 4096)

    char* ws = (char*)d_ws;
    int*            idxarr = (int*)(ws);                          // 256 KB
    unsigned short* Ball   = (unsigned short*)(ws + 262144);      // 1.5 MB
    unsigned short* Bs2    = (unsigned short*)(ws + 1835008);     // 384 KB
    unsigned short* emb_bf = (unsigned short*)(ws + 6422528);     // 8 MB
    unsigned short* G      = (unsigned short*)(ws + 14811136);    // 24 MB

    prep_kernel<<<1520, 256, 0, stream>>>(emb, dur, dp_w1, dp_w2, f0_w1,
                                          emb_bf, idxarr, Ball, Bs2);

    // GEMM + up-writer, role-interleaved (3:4 per 7-block chunk)
    guw_kernel<<<NGEMM + NUP, 256, 0, stream>>>(
        emb, emb_bf, idxarr, Ball, G, up);

    // f0 combine (reads G slabs 3-5)
    f0c_kernel<<<NB * NT / 64, 256, 0, stream>>>(
        idxarr, G, f0_b1, f0_g1, f0_be1, f0_w2, f0_b2, pf0);

    // fused dp chain (reads G slabs 0-2) -> pdur
    dpf_kernel<<<NROW / 32, 256, 0, stream>>>(
        G, dp_b1, dp_g1, dp_be1, Bs2, dp_b2, dp_g2, dp_be2,
        dp_w3, dp_b3, pdur);
}